// Round 1
// baseline (758.398 us; speedup 1.0000x reference)
//
#include <hip/hip_runtime.h>
#include <math.h>

#define BB 4
#define TT 4096
#define CC 1024
#define HS 64
#define MM (BB*TT)   // 16384

// ---------------------------------------------------------------------------
// QKV projection: out[M][HS] = x[M][C] @ W[C][HS], one of Wq/Wk/Wv per blockIdx.y
// block = 256 threads (16x16), 64x64 output tile, 4x4 register tile, K-chunk 32.
// ---------------------------------------------------------------------------
__global__ __launch_bounds__(256) void qkv_kernel(
    const float* __restrict__ x,
    const float* __restrict__ Wq,
    const float* __restrict__ Wk,
    const float* __restrict__ Wv,
    float* __restrict__ qkv)   // [3][M][HS]
{
    const int rt = blockIdx.x;        // row tile: 64 rows
    const int which = blockIdx.y;     // 0=q 1=k 2=v
    const float* __restrict__ W = (which == 0) ? Wq : (which == 1) ? Wk : Wv;
    float* __restrict__ out = qkv + (size_t)which * MM * HS;

    __shared__ float xs[64][36];      // 64 rows x 32 k, stride 36
    __shared__ float ws[32][68];      // 32 k x 64 n, stride 68

    const int t  = threadIdx.x;
    const int tr = t / 16;            // row group
    const int tc = t % 16;            // col group
    const int r0 = tr * 4, c0 = tc * 4;

    float acc[4][4] = {};

    for (int k0 = 0; k0 < CC; k0 += 32) {
        // x chunk: 64 rows x 32 floats = 512 float4, 2 per thread
        #pragma unroll
        for (int i = t; i < 512; i += 256) {
            int rr = i / 8;
            int cc = (i % 8) * 4;
            float4 v = *(const float4*)(x + (size_t)(rt * 64 + rr) * CC + k0 + cc);
            xs[rr][cc] = v.x; xs[rr][cc + 1] = v.y; xs[rr][cc + 2] = v.z; xs[rr][cc + 3] = v.w;
        }
        // W chunk: 32 k x 64 n = 512 float4, 2 per thread
        #pragma unroll
        for (int i = t; i < 512; i += 256) {
            int kk = i / 16;
            int nn = (i % 16) * 4;
            float4 v = *(const float4*)(W + (size_t)(k0 + kk) * HS + nn);
            ws[kk][nn] = v.x; ws[kk][nn + 1] = v.y; ws[kk][nn + 2] = v.z; ws[kk][nn + 3] = v.w;
        }
        __syncthreads();
        #pragma unroll 4
        for (int k = 0; k < 32; k++) {
            float a[4], b[4];
            #pragma unroll
            for (int i = 0; i < 4; i++) a[i] = xs[r0 + i][k];
            #pragma unroll
            for (int j = 0; j < 4; j++) b[j] = ws[k][c0 + j];
            #pragma unroll
            for (int i = 0; i < 4; i++)
                #pragma unroll
                for (int j = 0; j < 4; j++)
                    acc[i][j] += a[i] * b[j];
        }
        __syncthreads();
    }
    #pragma unroll
    for (int i = 0; i < 4; i++) {
        float4 v = make_float4(acc[i][0], acc[i][1], acc[i][2], acc[i][3]);
        *(float4*)(out + (size_t)(rt * 64 + r0 + i) * HS + c0) = v;
    }
}

// ---------------------------------------------------------------------------
// Flash attention (causal, no dropout). 32-query tile per block, 64-key tiles.
// block = 256 threads. grid = B * T/32 = 512, biggest qt launched first.
// LDS strides: qs/ps = 65 (conflict-free row-varying reads), ks/vs = 68
// (float4-aligned loads, <=2-way conflicts in hot loops).
// ---------------------------------------------------------------------------
#define QT 32
#define KT 64

__global__ __launch_bounds__(256) void attn_kernel(
    const float* __restrict__ qkv,
    float* __restrict__ out)   // [B][T][HS]
{
    const float* __restrict__ Q = qkv;
    const float* __restrict__ K = qkv + (size_t)MM * HS;
    const float* __restrict__ V = qkv + (size_t)2 * MM * HS;

    const int bid = blockIdx.x;
    const int b   = bid % BB;
    const int qt  = (TT / QT - 1) - (bid / BB);   // descending work order

    __shared__ float qs[QT][65];
    __shared__ float ks[KT][68];
    __shared__ float vs[KT][68];
    __shared__ float ps[QT][65];
    __shared__ float mrow[QT], lrow[QT], arow[QT];

    const int t = threadIdx.x;

    // load Q tile, pre-scaled by 1/sqrt(HS) = 0.125
    const float* __restrict__ Qb = Q + ((size_t)b * TT + qt * QT) * HS;
    #pragma unroll
    for (int i = t; i < QT * HS / 4; i += 256) {
        int rr = i / 16;
        int cc = (i % 16) * 4;
        float4 v = *(const float4*)(Qb + rr * HS + cc);
        qs[rr][cc] = v.x * 0.125f; qs[rr][cc + 1] = v.y * 0.125f;
        qs[rr][cc + 2] = v.z * 0.125f; qs[rr][cc + 3] = v.w * 0.125f;
    }
    if (t < QT) { mrow[t] = -1e30f; lrow[t] = 0.f; }

    // score mapping:  q0 = (t%16)*2, k0 = (t/16)*4
    const int tq = t % 16, tk = t / 16;
    const int q0 = tq * 2, k0 = tk * 4;
    // PV mapping:     qp = (t%16)*2, d0 = (t/16)*4
    const int d0 = tk * 4;

    float oacc[2][4] = {};

    const int nkt = (qt * QT + QT - 1) / KT + 1;
    for (int kt = 0; kt < nkt; kt++) {
        __syncthreads();   // prev PV done reading ks/vs/ps
        const float* __restrict__ Kb = K + ((size_t)b * TT + kt * KT) * HS;
        const float* __restrict__ Vb = V + ((size_t)b * TT + kt * KT) * HS;
        #pragma unroll
        for (int i = t; i < KT * HS / 4; i += 256) {
            int rr = i / 16;
            int cc = (i % 16) * 4;
            float4 v = *(const float4*)(Kb + rr * HS + cc);
            ks[rr][cc] = v.x; ks[rr][cc + 1] = v.y; ks[rr][cc + 2] = v.z; ks[rr][cc + 3] = v.w;
            float4 w = *(const float4*)(Vb + rr * HS + cc);
            vs[rr][cc] = w.x; vs[rr][cc + 1] = w.y; vs[rr][cc + 2] = w.z; vs[rr][cc + 3] = w.w;
        }
        __syncthreads();

        // ---- scores: 32x64, 2x4 per thread
        float s[2][4] = {};
        #pragma unroll 4
        for (int d = 0; d < HS; d++) {
            float a0 = qs[q0][d], a1 = qs[q0 + 1][d];
            float b0 = ks[k0][d], b1 = ks[k0 + 1][d], b2 = ks[k0 + 2][d], b3 = ks[k0 + 3][d];
            s[0][0] += a0 * b0; s[0][1] += a0 * b1; s[0][2] += a0 * b2; s[0][3] += a0 * b3;
            s[1][0] += a1 * b0; s[1][1] += a1 * b1; s[1][2] += a1 * b2; s[1][3] += a1 * b3;
        }
        #pragma unroll
        for (int i = 0; i < 2; i++) {
            int qg = qt * QT + q0 + i;
            #pragma unroll
            for (int j = 0; j < 4; j++) {
                int kg = kt * KT + k0 + j;
                ps[q0 + i][k0 + j] = (kg <= qg) ? s[i][j] : -1e30f;
            }
        }
        __syncthreads();

        // ---- online softmax, one thread per query row
        if (t < QT) {
            float mold = mrow[t];
            float mt = mold;
            #pragma unroll 8
            for (int k = 0; k < KT; k++) mt = fmaxf(mt, ps[t][k]);
            float alpha = __expf(mold - mt);
            float l = lrow[t] * alpha;
            #pragma unroll 8
            for (int k = 0; k < KT; k++) {
                float p = __expf(ps[t][k] - mt);
                ps[t][k] = p;
                l += p;
            }
            mrow[t] = mt; lrow[t] = l; arow[t] = alpha;
        }
        __syncthreads();

        // ---- PV: O = O*alpha + P@V, 2x4 per thread
        float al0 = arow[q0], al1 = arow[q0 + 1];
        #pragma unroll
        for (int j = 0; j < 4; j++) { oacc[0][j] *= al0; oacc[1][j] *= al1; }
        #pragma unroll 4
        for (int k = 0; k < KT; k++) {
            float p0 = ps[q0][k], p1 = ps[q0 + 1][k];
            float v0 = vs[k][d0], v1 = vs[k][d0 + 1], v2 = vs[k][d0 + 2], v3 = vs[k][d0 + 3];
            oacc[0][0] += p0 * v0; oacc[0][1] += p0 * v1; oacc[0][2] += p0 * v2; oacc[0][3] += p0 * v3;
            oacc[1][0] += p1 * v0; oacc[1][1] += p1 * v1; oacc[1][2] += p1 * v2; oacc[1][3] += p1 * v3;
        }
    }

    // ---- epilogue: divide by l, store
    float inv0 = 1.f / lrow[q0];
    float inv1 = 1.f / lrow[q0 + 1];
    float* __restrict__ ob = out + ((size_t)b * TT + qt * QT) * HS;
    float4 r0v = make_float4(oacc[0][0] * inv0, oacc[0][1] * inv0, oacc[0][2] * inv0, oacc[0][3] * inv0);
    float4 r1v = make_float4(oacc[1][0] * inv1, oacc[1][1] * inv1, oacc[1][2] * inv1, oacc[1][3] * inv1);
    *(float4*)(ob + (size_t)(q0) * HS + d0) = r0v;
    *(float4*)(ob + (size_t)(q0 + 1) * HS + d0) = r1v;
}

extern "C" void kernel_launch(void* const* d_in, const int* in_sizes, int n_in,
                              void* d_out, int out_size, void* d_ws, size_t ws_size,
                              hipStream_t stream) {
    const float* x  = (const float*)d_in[0];
    const float* Wq = (const float*)d_in[1];
    const float* Wk = (const float*)d_in[2];
    const float* Wv = (const float*)d_in[3];
    float* out = (float*)d_out;
    float* qkv = (float*)d_ws;   // 3 * M * HS floats = 12 MB

    qkv_kernel<<<dim3(MM / 64, 3), 256, 0, stream>>>(x, Wq, Wk, Wv, qkv);
    attn_kernel<<<BB * (TT / QT), 256, 0, stream>>>(qkv, out);
}

// Round 2
// 586.255 us; speedup vs baseline: 1.2936x; 1.2936x over previous
//
#include <hip/hip_runtime.h>
#include <math.h>

#define BB 4
#define TT 4096
#define CC 1024
#define HS 64
#define MM (BB*TT)   // 16384

// ---------------------------------------------------------------------------
// QKV projection: out[M][HS] = x[M][C] @ W[C][HS], one of Wq/Wk/Wv per blockIdx.y
// block = 256 threads (16x16), 64x64 output tile, 4x4 register tile, K-chunk 32.
// Register-prefetch of next chunk hides global latency under compute.
// ---------------------------------------------------------------------------
__global__ __launch_bounds__(256) void qkv_kernel(
    const float* __restrict__ x,
    const float* __restrict__ Wq,
    const float* __restrict__ Wk,
    const float* __restrict__ Wv,
    float* __restrict__ qkv)   // [3][M][HS]
{
    const int rt = blockIdx.x;        // row tile: 64 rows
    const int which = blockIdx.y;     // 0=q 1=k 2=v
    const float* __restrict__ W = (which == 0) ? Wq : (which == 1) ? Wk : Wv;
    float* __restrict__ out = qkv + (size_t)which * MM * HS;

    __shared__ float xs[64][36];      // 64 rows x 32 k, stride 36
    __shared__ float ws[32][68];      // 32 k x 64 n, stride 68

    const int t  = threadIdx.x;
    const int tr = t / 16;
    const int tc = t % 16;
    const int r0 = tr * 4, c0 = tc * 4;

    // staging index precompute (2 float4 each for x-chunk and W-chunk)
    const int xr_r[2] = { (t + 0)   / 8, (t + 256) / 8 };
    const int xr_c[2] = { ((t + 0)   % 8) * 4, ((t + 256) % 8) * 4 };
    const int wr_k[2] = { (t + 0)   / 16, (t + 256) / 16 };
    const int wr_n[2] = { ((t + 0)   % 16) * 4, ((t + 256) % 16) * 4 };

    float4 xreg[2], wreg[2];
    #pragma unroll
    for (int i = 0; i < 2; i++) {
        xreg[i] = *(const float4*)(x + (size_t)(rt * 64 + xr_r[i]) * CC + 0 + xr_c[i]);
        wreg[i] = *(const float4*)(W + (size_t)(0 + wr_k[i]) * HS + wr_n[i]);
    }

    float acc[4][4] = {};

    for (int k0 = 0; k0 < CC; k0 += 32) {
        __syncthreads();   // previous compute done reading xs/ws
        #pragma unroll
        for (int i = 0; i < 2; i++) {
            xs[xr_r[i]][xr_c[i] + 0] = xreg[i].x; xs[xr_r[i]][xr_c[i] + 1] = xreg[i].y;
            xs[xr_r[i]][xr_c[i] + 2] = xreg[i].z; xs[xr_r[i]][xr_c[i] + 3] = xreg[i].w;
            ws[wr_k[i]][wr_n[i] + 0] = wreg[i].x; ws[wr_k[i]][wr_n[i] + 1] = wreg[i].y;
            ws[wr_k[i]][wr_n[i] + 2] = wreg[i].z; ws[wr_k[i]][wr_n[i] + 3] = wreg[i].w;
        }
        if (k0 + 32 < CC) {
            #pragma unroll
            for (int i = 0; i < 2; i++) {
                xreg[i] = *(const float4*)(x + (size_t)(rt * 64 + xr_r[i]) * CC + (k0 + 32) + xr_c[i]);
                wreg[i] = *(const float4*)(W + (size_t)(k0 + 32 + wr_k[i]) * HS + wr_n[i]);
            }
        }
        __syncthreads();
        #pragma unroll 8
        for (int k = 0; k < 32; k++) {
            float a[4], b[4];
            #pragma unroll
            for (int i = 0; i < 4; i++) a[i] = xs[r0 + i][k];
            #pragma unroll
            for (int j = 0; j < 4; j++) b[j] = ws[k][c0 + j];
            #pragma unroll
            for (int i = 0; i < 4; i++)
                #pragma unroll
                for (int j = 0; j < 4; j++)
                    acc[i][j] += a[i] * b[j];
        }
    }
    #pragma unroll
    for (int i = 0; i < 4; i++) {
        float4 v = make_float4(acc[i][0], acc[i][1], acc[i][2], acc[i][3]);
        *(float4*)(out + (size_t)(rt * 64 + r0 + i) * HS + c0) = v;
    }
}

// ---------------------------------------------------------------------------
// Flash attention (causal). QT=32 queries/block, KT=64 key tile, 256 threads.
// 16-lane group per q-pair: q0=2*(t/16), k set {c,c+16,c+32,c+48}, c=t%16.
// Softmax fully parallel: row max/sum via __shfl_xor over the 16-lane group;
// m/l/alpha replicated in registers (no serial phase, no m/l LDS).
// PV: same group owns same q-pair, d0=4c -> alpha stays in-register,
// vs read as float4 (2-way bank = free). K/V register-prefetched.
// ---------------------------------------------------------------------------
#define QT 32
#define KT 64

__global__ __launch_bounds__(256) void attn_kernel(
    const float* __restrict__ qkv,
    float* __restrict__ out)   // [B][T][HS]
{
    const float* __restrict__ Q = qkv;
    const float* __restrict__ K = qkv + (size_t)MM * HS;
    const float* __restrict__ V = qkv + (size_t)2 * MM * HS;

    const int bid = blockIdx.x;
    const int b   = bid % BB;
    const int qt  = (TT / QT - 1) - (bid / BB);   // descending work (LPT-ish)

    __shared__ float qs[QT][65];
    __shared__ float ks[KT][68];
    __shared__ float vs[KT][68];
    __shared__ float ps[QT][65];

    const int t = threadIdx.x;
    const int g = t / 16;          // q-pair group 0..15 (wave-aligned)
    const int c = t % 16;
    const int q0 = 2 * g, q1 = 2 * g + 1;
    const int d0 = 4 * c;

    // load Q tile, pre-scaled by 1/sqrt(HS) = 0.125
    const float* __restrict__ Qb = Q + ((size_t)b * TT + qt * QT) * HS;
    #pragma unroll
    for (int i = t; i < QT * HS / 4; i += 256) {
        int rr = i / 16;
        int cc = (i % 16) * 4;
        float4 v = *(const float4*)(Qb + rr * HS + cc);
        qs[rr][cc] = v.x * 0.125f; qs[rr][cc + 1] = v.y * 0.125f;
        qs[rr][cc + 2] = v.z * 0.125f; qs[rr][cc + 3] = v.w * 0.125f;
    }

    // staging assignment: 4 float4 per thread for each of K,V
    const int st_r[4] = { t / 16, 16 + t / 16, 32 + t / 16, 48 + t / 16 };
    const int st_c    = (t % 16) * 4;

    const int nkt = (qt * QT + QT - 1) / KT + 1;
    const float* __restrict__ Kb = K + (size_t)b * TT * HS;
    const float* __restrict__ Vb = V + (size_t)b * TT * HS;

    float4 kreg[4], vreg[4];
    #pragma unroll
    for (int i = 0; i < 4; i++) {
        kreg[i] = *(const float4*)(Kb + (size_t)st_r[i] * HS + st_c);
        vreg[i] = *(const float4*)(Vb + (size_t)st_r[i] * HS + st_c);
    }

    float m0 = -1e30f, m1 = -1e30f, l0 = 0.f, l1 = 0.f;
    float oacc[2][4] = {};

    for (int kt = 0; kt < nkt; kt++) {
        __syncthreads();   // prev PV done reading ks/vs
        #pragma unroll
        for (int i = 0; i < 4; i++) {
            *(float4*)(&ks[st_r[i]][st_c]) = kreg[i];
            *(float4*)(&vs[st_r[i]][st_c]) = vreg[i];
        }
        if (kt + 1 < nkt) {
            const size_t base = (size_t)(kt + 1) * KT * HS;
            #pragma unroll
            for (int i = 0; i < 4; i++) {
                kreg[i] = *(const float4*)(Kb + base + (size_t)st_r[i] * HS + st_c);
                vreg[i] = *(const float4*)(Vb + base + (size_t)st_r[i] * HS + st_c);
            }
        }
        __syncthreads();   // ks/vs visible

        // ---- scores: 2 rows x 4 k per thread, k = c + 16j
        float s0[4] = {}, s1[4] = {};
        #pragma unroll 8
        for (int d = 0; d < HS; d++) {
            float a0 = qs[q0][d], a1 = qs[q1][d];
            #pragma unroll
            for (int j = 0; j < 4; j++) {
                float bk = ks[c + 16 * j][d];
                s0[j] += a0 * bk;
                s1[j] += a1 * bk;
            }
        }
        // causal mask
        const int qg0 = qt * QT + q0, qg1 = qg0 + 1;
        #pragma unroll
        for (int j = 0; j < 4; j++) {
            int kg = kt * KT + c + 16 * j;
            if (kg > qg0) s0[j] = -1e30f;
            if (kg > qg1) s1[j] = -1e30f;
        }

        // ---- parallel online softmax (shuffle over 16-lane group)
        float mt0 = fmaxf(fmaxf(s0[0], s0[1]), fmaxf(s0[2], s0[3]));
        float mt1 = fmaxf(fmaxf(s1[0], s1[1]), fmaxf(s1[2], s1[3]));
        #pragma unroll
        for (int msk = 1; msk < 16; msk <<= 1) {
            mt0 = fmaxf(mt0, __shfl_xor(mt0, msk));
            mt1 = fmaxf(mt1, __shfl_xor(mt1, msk));
        }
        float mn0 = fmaxf(m0, mt0), mn1 = fmaxf(m1, mt1);
        float alpha0 = __expf(m0 - mn0), alpha1 = __expf(m1 - mn1);
        float ts0 = 0.f, ts1 = 0.f;
        float p0[4], p1[4];
        #pragma unroll
        for (int j = 0; j < 4; j++) {
            p0[j] = __expf(s0[j] - mn0);
            p1[j] = __expf(s1[j] - mn1);
            ts0 += p0[j]; ts1 += p1[j];
        }
        #pragma unroll
        for (int msk = 1; msk < 16; msk <<= 1) {
            ts0 += __shfl_xor(ts0, msk);
            ts1 += __shfl_xor(ts1, msk);
        }
        l0 = l0 * alpha0 + ts0;
        l1 = l1 * alpha1 + ts1;
        m0 = mn0; m1 = mn1;
        #pragma unroll
        for (int j = 0; j < 4; j++) {
            ps[q0][c + 16 * j] = p0[j];
            ps[q1][c + 16 * j] = p1[j];
        }
        __syncthreads();   // ps visible

        // ---- PV: O = O*alpha + P@V, 2 rows x 4 d (d0=4c) per thread
        #pragma unroll
        for (int j = 0; j < 4; j++) { oacc[0][j] *= alpha0; oacc[1][j] *= alpha1; }
        #pragma unroll 4
        for (int k = 0; k < KT; k++) {
            float pa = ps[q0][k], pb = ps[q1][k];
            float4 v = *(const float4*)(&vs[k][d0]);
            oacc[0][0] += pa * v.x; oacc[0][1] += pa * v.y;
            oacc[0][2] += pa * v.z; oacc[0][3] += pa * v.w;
            oacc[1][0] += pb * v.x; oacc[1][1] += pb * v.y;
            oacc[1][2] += pb * v.z; oacc[1][3] += pb * v.w;
        }
    }

    // ---- epilogue
    float inv0 = 1.f / l0, inv1 = 1.f / l1;
    float* __restrict__ ob = out + ((size_t)b * TT + qt * QT) * HS;
    float4 r0v = make_float4(oacc[0][0] * inv0, oacc[0][1] * inv0, oacc[0][2] * inv0, oacc[0][3] * inv0);
    float4 r1v = make_float4(oacc[1][0] * inv1, oacc[1][1] * inv1, oacc[1][2] * inv1, oacc[1][3] * inv1);
    *(float4*)(ob + (size_t)q0 * HS + d0) = r0v;
    *(float4*)(ob + (size_t)q1 * HS + d0) = r1v;
}

extern "C" void kernel_launch(void* const* d_in, const int* in_sizes, int n_in,
                              void* d_out, int out_size, void* d_ws, size_t ws_size,
                              hipStream_t stream) {
    const float* x  = (const float*)d_in[0];
    const float* Wq = (const float*)d_in[1];
    const float* Wk = (const float*)d_in[2];
    const float* Wv = (const float*)d_in[3];
    float* out = (float*)d_out;
    float* qkv = (float*)d_ws;   // 3 * M * HS floats = 12 MB

    qkv_kernel<<<dim3(MM / 64, 3), 256, 0, stream>>>(x, Wq, Wk, Wv, qkv);
    attn_kernel<<<BB * (TT / QT), 256, 0, stream>>>(qkv, out);
}

// Round 3
// 202.968 us; speedup vs baseline: 3.7365x; 2.8884x over previous
//
#include <hip/hip_runtime.h>
#include <math.h>

#define BB 4
#define TT 4096
#define CC 1024
#define HS 64
#define MM (BB*TT)   // 16384

typedef __attribute__((ext_vector_type(8))) short short8;    // 8 bf16 (4 VGPR)
typedef __attribute__((ext_vector_type(4))) float f32x4;     // MFMA acc
typedef __attribute__((ext_vector_type(4))) unsigned short ushort4v;

__device__ __forceinline__ unsigned short f2bf(float f) {   // RNE fp32->bf16
    union { float f; unsigned u; } v; v.f = f;
    return (unsigned short)((v.u + 0x7fffu + ((v.u >> 16) & 1u)) >> 16);
}

// ---------------------------------------------------------------------------
// prep: Wt[3][64][1024] = W^T as bf16; Wq pre-scaled by 1/sqrt(HS)=0.125 (exact)
// ---------------------------------------------------------------------------
__global__ __launch_bounds__(256) void prep_kernel(
    const float* __restrict__ Wq, const float* __restrict__ Wk,
    const float* __restrict__ Wv, unsigned short* __restrict__ Wt)
{
    int id = blockIdx.x * 256 + threadIdx.x;
    if (id < 3 * 64 * 1024) {
        int which = id >> 16;
        int n = (id >> 10) & 63;
        int k = id & 1023;
        const float* W = (which == 0) ? Wq : (which == 1) ? Wk : Wv;
        float v = W[k * 64 + n];
        if (which == 0) v *= 0.125f;
        Wt[id] = f2bf(v);
    }
}

// ---------------------------------------------------------------------------
// qkv_mfma: [q|k|v](64-row tile x 192 cols) = x_tile(64x1024) @ [Wq|Wk|Wv]
// 256 thr / 4 waves; wave w owns n-tiles {w, 4+w, 8+w} (one q, one k, one v
// 16-col tile) x 4 m-tiles -> 12 C-frags. K-chunk 64, reg-prefetched staging.
// V written transposed (vT[b][d][t], bf16) via LDS transpose for attn PV frags.
// LDS strides 72 bf16 (144B): 16B-aligned b128 frag reads, 2-way banks (free).
// ---------------------------------------------------------------------------
__global__ __launch_bounds__(256) void qkv_mfma(
    const float* __restrict__ x, const unsigned short* __restrict__ Wt,
    unsigned short* __restrict__ qb, unsigned short* __restrict__ kb,
    unsigned short* __restrict__ vT)
{
    const int rt = blockIdx.x;                 // 64-row tile, 256 blocks
    __shared__ unsigned short xs[64][72];      // 64 rows x 64 k
    __shared__ unsigned short ws[192][72];     // 192 n x 64 k (W^T tile)

    const int t = threadIdx.x;
    const int w = t >> 6;                      // wave 0..3
    const int lane = t & 63;
    const int quad = lane >> 4;
    const int c = lane & 15;

    // staging prefetch (chunk 0)
    float4 xreg[4];
    short8 wreg[6];
    #pragma unroll
    for (int i = 0; i < 4; i++) {
        int idx = t + 256 * i;
        int r = idx >> 4, c4 = (idx & 15) * 4;
        xreg[i] = *(const float4*)(x + (size_t)(rt * 64 + r) * CC + c4);
    }
    #pragma unroll
    for (int i = 0; i < 6; i++) {
        int idx = t + 256 * i;
        int n = idx >> 3, c8 = (idx & 7) * 8;
        wreg[i] = *(const short8*)(Wt + (size_t)n * CC + c8);
    }

    f32x4 acc[4][3];
    #pragma unroll
    for (int mt = 0; mt < 4; mt++)
        #pragma unroll
        for (int j = 0; j < 3; j++) acc[mt][j] = (f32x4){0.f, 0.f, 0.f, 0.f};

    for (int k0 = 0; k0 < CC; k0 += 64) {
        __syncthreads();
        #pragma unroll
        for (int i = 0; i < 4; i++) {
            int idx = t + 256 * i;
            int r = idx >> 4, c4 = (idx & 15) * 4;
            ushort4v p = { f2bf(xreg[i].x), f2bf(xreg[i].y), f2bf(xreg[i].z), f2bf(xreg[i].w) };
            *(ushort4v*)&xs[r][c4] = p;
        }
        #pragma unroll
        for (int i = 0; i < 6; i++) {
            int idx = t + 256 * i;
            int n = idx >> 3, c8 = (idx & 7) * 8;
            *(short8*)&ws[n][c8] = wreg[i];
        }
        if (k0 + 64 < CC) {
            #pragma unroll
            for (int i = 0; i < 4; i++) {
                int idx = t + 256 * i;
                int r = idx >> 4, c4 = (idx & 15) * 4;
                xreg[i] = *(const float4*)(x + (size_t)(rt * 64 + r) * CC + k0 + 64 + c4);
            }
            #pragma unroll
            for (int i = 0; i < 6; i++) {
                int idx = t + 256 * i;
                int n = idx >> 3, c8 = (idx & 7) * 8;
                wreg[i] = *(const short8*)(Wt + (size_t)n * CC + k0 + 64 + c8);
            }
        }
        __syncthreads();
        #pragma unroll
        for (int ks = 0; ks < 2; ks++) {
            short8 af[4], bf[3];
            #pragma unroll
            for (int mt = 0; mt < 4; mt++)
                af[mt] = *(const short8*)&xs[16 * mt + c][ks * 32 + quad * 8];
            #pragma unroll
            for (int j = 0; j < 3; j++)
                bf[j] = *(const short8*)&ws[16 * (w + 4 * j) + c][ks * 32 + quad * 8];
            #pragma unroll
            for (int mt = 0; mt < 4; mt++)
                #pragma unroll
                for (int j = 0; j < 3; j++)
                    acc[mt][j] = __builtin_amdgcn_mfma_f32_16x16x32_bf16(af[mt], bf[j], acc[mt][j], 0, 0, 0);
        }
    }

    // epilogue: q,k direct bf16 stores; v -> LDS transpose (reuse xs) -> vT
    __syncthreads();   // xs free now
    unsigned short (*vtb)[72] = xs;  // [d 0..63][t-local 0..63]
    #pragma unroll
    for (int mt = 0; mt < 4; mt++) {
        int grow = rt * 64 + 16 * mt + quad * 4;
        #pragma unroll
        for (int reg = 0; reg < 4; reg++) {
            qb[(size_t)(grow + reg) * HS + 16 * w + c] = f2bf(acc[mt][0][reg]);
            kb[(size_t)(grow + reg) * HS + 16 * w + c] = f2bf(acc[mt][1][reg]);
            vtb[16 * w + c][16 * mt + quad * 4 + reg] = f2bf(acc[mt][2][reg]);
        }
    }
    __syncthreads();
    {
        const int b  = rt >> 6;                 // 4096/64 tiles per batch
        const int t0 = (rt & 63) * 64;
        int d = t >> 2, c16 = (t & 3) * 16;
        short8 v0 = *(const short8*)&vtb[d][c16];
        short8 v1 = *(const short8*)&vtb[d][c16 + 8];
        unsigned short* dst = vT + (size_t)b * HS * TT + (size_t)d * TT + t0 + c16;
        *(short8*)dst = v0;
        *(short8*)(dst + 8) = v1;
    }
}

// ---------------------------------------------------------------------------
// attn_mfma: flash attention, bf16 MFMA. 128 thr / 2 waves; wave owns 16
// queries (QT=32/block), KT=64 keys/iter. QK^T: A=Q(reg-resident), B=ks.
// Softmax per-lane on C-frags (rows quad*4+reg), 16-lane shfl reductions.
// P round-trips per-wave-private LDS (bf16, no barrier) to A-layout; PV B=vt.
// grid 512 (b,qt desc); last K-tile masked only (tile-aligned causality).
// ---------------------------------------------------------------------------
__global__ __launch_bounds__(128) void attn_mfma(
    const unsigned short* __restrict__ qb, const unsigned short* __restrict__ kb,
    const unsigned short* __restrict__ vT, float* __restrict__ out)
{
    const int bid = blockIdx.x;
    const int b   = bid & 3;
    const int qt  = (TT / 32 - 1) - (bid >> 2);   // descending work
    const int qbase = qt * 32;

    __shared__ unsigned short ks[64][72];      // [key][d]
    __shared__ unsigned short vt[64][72];      // [d][key]
    __shared__ unsigned short ps[2][16][72];   // per-wave P  [q][key]

    const int t = threadIdx.x;
    const int w = t >> 6;
    const int lane = t & 63;
    const int quad = lane >> 4;
    const int c = lane & 15;
    const int qrow = qbase + 16 * w;           // wave's first query row

    // Q A-frags resident in registers (2 k-steps over HS=64)
    short8 aq[2];
    #pragma unroll
    for (int kstep = 0; kstep < 2; kstep++)
        aq[kstep] = *(const short8*)(qb + (size_t)(b * TT + qrow + c) * HS + kstep * 32 + quad * 8);

    const int nkt = qt / 2 + 1;
    const unsigned short* Kb = kb + (size_t)b * TT * HS;
    const unsigned short* Vb = vT + (size_t)b * HS * TT;

    short8 kreg[4], vreg[4];
    #pragma unroll
    for (int i = 0; i < 4; i++) {
        int idx = t + 128 * i;
        int row = idx >> 3, c8 = (idx & 7) * 8;
        kreg[i] = *(const short8*)(Kb + (size_t)row * HS + c8);
        vreg[i] = *(const short8*)(Vb + (size_t)row * TT + c8);
    }

    float m[4], l[4];
    #pragma unroll
    for (int r = 0; r < 4; r++) { m[r] = -1e30f; l[r] = 0.f; }
    f32x4 oacc[4];
    #pragma unroll
    for (int dt = 0; dt < 4; dt++) oacc[dt] = (f32x4){0.f, 0.f, 0.f, 0.f};

    for (int kt = 0; kt < nkt; kt++) {
        const int kt0 = kt * 64;
        __syncthreads();
        #pragma unroll
        for (int i = 0; i < 4; i++) {
            int idx = t + 128 * i;
            int row = idx >> 3, c8 = (idx & 7) * 8;
            *(short8*)&ks[row][c8] = kreg[i];
            *(short8*)&vt[row][c8] = vreg[i];
        }
        if (kt + 1 < nkt) {
            #pragma unroll
            for (int i = 0; i < 4; i++) {
                int idx = t + 128 * i;
                int row = idx >> 3, c8 = (idx & 7) * 8;
                kreg[i] = *(const short8*)(Kb + (size_t)(kt0 + 64 + row) * HS + c8);
                vreg[i] = *(const short8*)(Vb + (size_t)row * TT + kt0 + 64 + c8);
            }
        }
        __syncthreads();

        // ---- scores: 4 key-subtiles of 16
        f32x4 s[4];
        #pragma unroll
        for (int st = 0; st < 4; st++) s[st] = (f32x4){0.f, 0.f, 0.f, 0.f};
        #pragma unroll
        for (int kstep = 0; kstep < 2; kstep++) {
            #pragma unroll
            for (int st = 0; st < 4; st++) {
                short8 bf = *(const short8*)&ks[16 * st + c][kstep * 32 + quad * 8];
                s[st] = __builtin_amdgcn_mfma_f32_16x16x32_bf16(aq[kstep], bf, s[st], 0, 0, 0);
            }
        }
        // causal mask (only the diagonal tile needs it)
        if (kt == nkt - 1) {
            #pragma unroll
            for (int st = 0; st < 4; st++)
                #pragma unroll
                for (int reg = 0; reg < 4; reg++) {
                    int kg = kt0 + 16 * st + c;
                    int qg = qrow + quad * 4 + reg;
                    if (kg > qg) s[st][reg] = -1e30f;
                }
        }

        // ---- online softmax (per lane: 4 rows quad*4+reg)
        float rmax[4], rsum[4], alpha[4];
        #pragma unroll
        for (int reg = 0; reg < 4; reg++) {
            float mt_ = fmaxf(fmaxf(s[0][reg], s[1][reg]), fmaxf(s[2][reg], s[3][reg]));
            #pragma unroll
            for (int msk = 1; msk < 16; msk <<= 1) mt_ = fmaxf(mt_, __shfl_xor(mt_, msk));
            rmax[reg] = mt_;
        }
        #pragma unroll
        for (int reg = 0; reg < 4; reg++) {
            float mn = fmaxf(m[reg], rmax[reg]);
            alpha[reg] = __expf(m[reg] - mn);
            m[reg] = mn;
            float ts = 0.f;
            #pragma unroll
            for (int st = 0; st < 4; st++) {
                float p = __expf(s[st][reg] - mn);
                s[st][reg] = p;
                ts += p;
            }
            rsum[reg] = ts;
        }
        #pragma unroll
        for (int reg = 0; reg < 4; reg++) {
            float ts = rsum[reg];
            #pragma unroll
            for (int msk = 1; msk < 16; msk <<= 1) ts += __shfl_xor(ts, msk);
            l[reg] = l[reg] * alpha[reg] + ts;
        }
        // P -> LDS (C-layout write, per-wave private; same-wave readback)
        #pragma unroll
        for (int st = 0; st < 4; st++)
            #pragma unroll
            for (int reg = 0; reg < 4; reg++)
                ps[w][quad * 4 + reg][16 * st + c] = f2bf(s[st][reg]);

        // ---- PV: O = O*alpha + P@V
        #pragma unroll
        for (int dt = 0; dt < 4; dt++)
            #pragma unroll
            for (int reg = 0; reg < 4; reg++) oacc[dt][reg] *= alpha[reg];
        #pragma unroll
        for (int kstep = 0; kstep < 2; kstep++) {
            short8 ap = *(const short8*)&ps[w][c][kstep * 32 + quad * 8];
            #pragma unroll
            for (int dt = 0; dt < 4; dt++) {
                short8 bv = *(const short8*)&vt[16 * dt + c][kstep * 32 + quad * 8];
                oacc[dt] = __builtin_amdgcn_mfma_f32_16x16x32_bf16(ap, bv, oacc[dt], 0, 0, 0);
            }
        }
    }

    // ---- epilogue
    float inv[4];
    #pragma unroll
    for (int reg = 0; reg < 4; reg++) inv[reg] = 1.f / l[reg];
    #pragma unroll
    for (int dt = 0; dt < 4; dt++)
        #pragma unroll
        for (int reg = 0; reg < 4; reg++)
            out[(size_t)(b * TT + qrow + quad * 4 + reg) * HS + 16 * dt + c] = oacc[dt][reg] * inv[reg];
}

extern "C" void kernel_launch(void* const* d_in, const int* in_sizes, int n_in,
                              void* d_out, int out_size, void* d_ws, size_t ws_size,
                              hipStream_t stream) {
    const float* x  = (const float*)d_in[0];
    const float* Wq = (const float*)d_in[1];
    const float* Wk = (const float*)d_in[2];
    const float* Wv = (const float*)d_in[3];
    float* out = (float*)d_out;

    unsigned short* Wt = (unsigned short*)d_ws;                  // 3*64*1024 bf16 = 384 KB
    unsigned short* qbuf = Wt + 3 * 64 * 1024;                   // 16384*64 bf16 = 2 MB
    unsigned short* kbuf = qbuf + (size_t)MM * HS;
    unsigned short* vTb  = kbuf + (size_t)MM * HS;               // [4][64][4096]

    prep_kernel<<<768, 256, 0, stream>>>(Wq, Wk, Wv, Wt);
    qkv_mfma<<<MM / 64, 256, 0, stream>>>(x, Wt, qbuf, kbuf, vTb);
    attn_mfma<<<BB * (TT / 32), 128, 0, stream>>>(qbuf, kbuf, vTb, out);
}

// Round 4
// 150.167 us; speedup vs baseline: 5.0504x; 1.3516x over previous
//
#include <hip/hip_runtime.h>
#include <math.h>

#define BB 4
#define TT 4096
#define CC 1024
#define HS 64
#define MM (BB*TT)   // 16384

typedef __attribute__((ext_vector_type(8))) short short8;    // 8 bf16 (4 VGPR)
typedef __attribute__((ext_vector_type(4))) float f32x4;     // MFMA acc
typedef __attribute__((ext_vector_type(4))) unsigned short ushort4v;

__device__ __forceinline__ unsigned short f2bf(float f) {   // RNE fp32->bf16
    union { float f; unsigned u; } v; v.f = f;
    return (unsigned short)((v.u + 0x7fffu + ((v.u >> 16) & 1u)) >> 16);
}

// ---------------------------------------------------------------------------
// prep: Wt[3][64][1024] = W^T as bf16; Wq pre-scaled by 1/sqrt(HS)=0.125 (exact)
// ---------------------------------------------------------------------------
__global__ __launch_bounds__(256) void prep_kernel(
    const float* __restrict__ Wq, const float* __restrict__ Wk,
    const float* __restrict__ Wv, unsigned short* __restrict__ Wt)
{
    int id = blockIdx.x * 256 + threadIdx.x;
    if (id < 3 * 64 * 1024) {
        int which = id >> 16;
        int n = (id >> 10) & 63;
        int k = id & 1023;
        const float* W = (which == 0) ? Wq : (which == 1) ? Wk : Wv;
        float v = W[k * 64 + n];
        if (which == 0) v *= 0.125f;
        Wt[id] = f2bf(v);
    }
}

// ---------------------------------------------------------------------------
// qkv_mfma: 32-row m-tile x 192 cols, 512 blocks (2/CU), 256 thr / 4 waves.
// Wave w owns n-tiles {w, 4+w, 8+w} (one q, one k, one v col-tile) x 2 m-tiles.
// K-chunk 64, reg-prefetched. V emitted transposed (vT[b][d][t]) via LDS.
// ---------------------------------------------------------------------------
__global__ __launch_bounds__(256) void qkv_mfma(
    const float* __restrict__ x, const unsigned short* __restrict__ Wt,
    unsigned short* __restrict__ qb, unsigned short* __restrict__ kb,
    unsigned short* __restrict__ vT)
{
    const int rt = blockIdx.x;                 // 32-row tile, 512 blocks
    __shared__ unsigned short xs[64][72];      // rows 0..31 = x-tile; epilogue: v^T buf [d][t]
    __shared__ unsigned short ws[192][72];     // 192 n x 64 k (W^T tile)

    const int t = threadIdx.x;
    const int w = t >> 6;
    const int lane = t & 63;
    const int quad = lane >> 4;
    const int c = lane & 15;

    // staging prefetch (chunk 0): x 2 float4, W 6 short8 per thread
    float4 xreg[2];
    short8 wreg[6];
    #pragma unroll
    for (int i = 0; i < 2; i++) {
        int idx = t + 256 * i;
        int r = idx >> 4, c4 = (idx & 15) * 4;
        xreg[i] = *(const float4*)(x + (size_t)(rt * 32 + r) * CC + c4);
    }
    #pragma unroll
    for (int i = 0; i < 6; i++) {
        int idx = t + 256 * i;
        int n = idx >> 3, c8 = (idx & 7) * 8;
        wreg[i] = *(const short8*)(Wt + (size_t)n * CC + c8);
    }

    f32x4 acc[2][3];
    #pragma unroll
    for (int mt = 0; mt < 2; mt++)
        #pragma unroll
        for (int j = 0; j < 3; j++) acc[mt][j] = (f32x4){0.f, 0.f, 0.f, 0.f};

    for (int k0 = 0; k0 < CC; k0 += 64) {
        __syncthreads();
        #pragma unroll
        for (int i = 0; i < 2; i++) {
            int idx = t + 256 * i;
            int r = idx >> 4, c4 = (idx & 15) * 4;
            ushort4v p = { f2bf(xreg[i].x), f2bf(xreg[i].y), f2bf(xreg[i].z), f2bf(xreg[i].w) };
            *(ushort4v*)&xs[r][c4] = p;
        }
        #pragma unroll
        for (int i = 0; i < 6; i++) {
            int idx = t + 256 * i;
            int n = idx >> 3, c8 = (idx & 7) * 8;
            *(short8*)&ws[n][c8] = wreg[i];
        }
        if (k0 + 64 < CC) {
            #pragma unroll
            for (int i = 0; i < 2; i++) {
                int idx = t + 256 * i;
                int r = idx >> 4, c4 = (idx & 15) * 4;
                xreg[i] = *(const float4*)(x + (size_t)(rt * 32 + r) * CC + k0 + 64 + c4);
            }
            #pragma unroll
            for (int i = 0; i < 6; i++) {
                int idx = t + 256 * i;
                int n = idx >> 3, c8 = (idx & 7) * 8;
                wreg[i] = *(const short8*)(Wt + (size_t)n * CC + k0 + 64 + c8);
            }
        }
        __syncthreads();
        #pragma unroll
        for (int ks = 0; ks < 2; ks++) {
            short8 af[2], bf[3];
            #pragma unroll
            for (int mt = 0; mt < 2; mt++)
                af[mt] = *(const short8*)&xs[16 * mt + c][ks * 32 + quad * 8];
            #pragma unroll
            for (int j = 0; j < 3; j++)
                bf[j] = *(const short8*)&ws[16 * (w + 4 * j) + c][ks * 32 + quad * 8];
            #pragma unroll
            for (int mt = 0; mt < 2; mt++)
                #pragma unroll
                for (int j = 0; j < 3; j++)
                    acc[mt][j] = __builtin_amdgcn_mfma_f32_16x16x32_bf16(af[mt], bf[j], acc[mt][j], 0, 0, 0);
        }
    }

    // epilogue: q,k direct bf16 stores; v -> LDS transpose (reuse xs) -> vT
    __syncthreads();
    unsigned short (*vtb)[72] = xs;  // [d 0..63][t-local 0..31]
    #pragma unroll
    for (int mt = 0; mt < 2; mt++) {
        int grow = rt * 32 + 16 * mt + quad * 4;
        #pragma unroll
        for (int reg = 0; reg < 4; reg++) {
            qb[(size_t)(grow + reg) * HS + 16 * w + c] = f2bf(acc[mt][0][reg]);
            kb[(size_t)(grow + reg) * HS + 16 * w + c] = f2bf(acc[mt][1][reg]);
            vtb[16 * w + c][16 * mt + quad * 4 + reg] = f2bf(acc[mt][2][reg]);
        }
    }
    __syncthreads();
    {
        const int b  = rt >> 7;                 // 128 tiles per batch
        const int t0 = (rt & 127) * 32;
        int d = t >> 2, c8 = (t & 3) * 8;
        short8 v0 = *(const short8*)&vtb[d][c8];
        *(short8*)(vT + (size_t)b * HS * TT + (size_t)d * TT + t0 + c8) = v0;
    }
}

// ---------------------------------------------------------------------------
// attn_mfma: causal flash attention, bf16 MFMA, NO online rescale.
// Fixed softmax shift (=0) is safe: |s| = |q.k|/8 <= ~8, exp fits fp32 easily.
// -> p = exp(s), l accumulates per-lane, ONE reduction in epilogue.
// 256 thr / 4 waves = (2 q-halves) x (2 K-parities); 128-key super-tile staged
// per barrier-pair; parity partials (O,l unnormalized) summed at the end.
// Grid 512 (b x 128 q-tiles, qt descending), 2 blocks/CU.
// ---------------------------------------------------------------------------
__global__ __launch_bounds__(256) void attn_mfma(
    const unsigned short* __restrict__ qb, const unsigned short* __restrict__ kb,
    const unsigned short* __restrict__ vT, float* __restrict__ out)
{
    const int bid = blockIdx.x;
    const int b   = bid & 3;
    const int qt  = (TT / 32 - 1) - (bid >> 2);
    const int qbase = qt * 32;

    __shared__ unsigned short ks[128][72];     // [key-local][d]
    __shared__ unsigned short vt[64][136];     // [d][key-local 0..127]
    __shared__ unsigned short ps[4][16][72];   // per-wave P [q][key]
    __shared__ float obuf[2][16][68];          // parity-1 O partials [qh][q][d]
    __shared__ float lbuf[2][16];              // parity-1 l partials

    const int t = threadIdx.x;
    const int w = t >> 6;
    const int lane = t & 63;
    const int quad = lane >> 4;
    const int c = lane & 15;
    const int qh = w & 1;                      // q-half (16 queries)
    const int kp = w >> 1;                     // K-parity
    const int qrow = qbase + 16 * qh;

    // Q A-frags resident in registers
    short8 aq[2];
    #pragma unroll
    for (int kstep = 0; kstep < 2; kstep++)
        aq[kstep] = *(const short8*)(qb + (size_t)(b * TT + qrow + c) * HS + kstep * 32 + quad * 8);

    const int ns = qt / 4 + 1;                 // 128-key super-tiles
    const unsigned short* Kb = kb + (size_t)b * TT * HS;
    const unsigned short* Vb = vT + (size_t)b * HS * TT;

    // staging maps: K 4 short8 (rows 0..127), V 4 short8 (rows 0..63 x 128 cols)
    short8 kreg[4], vreg[4];
    #pragma unroll
    for (int i = 0; i < 4; i++) {
        int idx = t + 256 * i;
        int krow = idx >> 3, kc8 = (idx & 7) * 8;
        kreg[i] = *(const short8*)(Kb + (size_t)krow * HS + kc8);
        int vrow = idx >> 4, vc8 = (idx & 15) * 8;
        vreg[i] = *(const short8*)(Vb + (size_t)vrow * TT + vc8);
    }

    float l[4] = {0.f, 0.f, 0.f, 0.f};
    f32x4 oacc[4];
    #pragma unroll
    for (int dt = 0; dt < 4; dt++) oacc[dt] = (f32x4){0.f, 0.f, 0.f, 0.f};

    for (int s = 0; s < ns; s++) {
        __syncthreads();   // prev compute done reading ks/vt
        #pragma unroll
        for (int i = 0; i < 4; i++) {
            int idx = t + 256 * i;
            int krow = idx >> 3, kc8 = (idx & 7) * 8;
            *(short8*)&ks[krow][kc8] = kreg[i];
            int vrow = idx >> 4, vc8 = (idx & 15) * 8;
            *(short8*)&vt[vrow][vc8] = vreg[i];
        }
        if (s + 1 < ns) {
            const int base = 128 * (s + 1);
            #pragma unroll
            for (int i = 0; i < 4; i++) {
                int idx = t + 256 * i;
                int krow = idx >> 3, kc8 = (idx & 7) * 8;
                kreg[i] = *(const short8*)(Kb + (size_t)(base + krow) * HS + kc8);
                int vrow = idx >> 4, vc8 = (idx & 15) * 8;
                vreg[i] = *(const short8*)(Vb + (size_t)vrow * TT + base + vc8);
            }
        }
        __syncthreads();   // ks/vt visible

        const int kt0 = 128 * s + 64 * kp;     // this wave's 64-key tile start
        if (kt0 <= qbase + 31) {               // wave-uniform: any valid keys?
            // ---- scores
            f32x4 sc[4];
            #pragma unroll
            for (int st = 0; st < 4; st++) sc[st] = (f32x4){0.f, 0.f, 0.f, 0.f};
            #pragma unroll
            for (int kstep = 0; kstep < 2; kstep++) {
                #pragma unroll
                for (int st = 0; st < 4; st++) {
                    short8 bf = *(const short8*)&ks[64 * kp + 16 * st + c][kstep * 32 + quad * 8];
                    sc[st] = __builtin_amdgcn_mfma_f32_16x16x32_bf16(aq[kstep], bf, sc[st], 0, 0, 0);
                }
            }
            // ---- p = exp(s) (fixed shift), mask diagonal tile to 0
            if (kt0 + 63 >= qrow) {            // tile straddles diagonal
                #pragma unroll
                for (int st = 0; st < 4; st++)
                    #pragma unroll
                    for (int reg = 0; reg < 4; reg++) {
                        int kg = kt0 + 16 * st + c;
                        int qg = qrow + quad * 4 + reg;
                        float p = (kg <= qg) ? __expf(sc[st][reg]) : 0.f;
                        sc[st][reg] = p;
                        l[reg] += p;
                    }
            } else {
                #pragma unroll
                for (int st = 0; st < 4; st++)
                    #pragma unroll
                    for (int reg = 0; reg < 4; reg++) {
                        float p = __expf(sc[st][reg]);
                        sc[st][reg] = p;
                        l[reg] += p;
                    }
            }
            // ---- P -> per-wave LDS (C-layout write, A-layout read; same wave)
            #pragma unroll
            for (int st = 0; st < 4; st++)
                #pragma unroll
                for (int reg = 0; reg < 4; reg++)
                    ps[w][quad * 4 + reg][16 * st + c] = f2bf(sc[st][reg]);

            // ---- PV accumulate (unnormalized)
            #pragma unroll
            for (int kstep = 0; kstep < 2; kstep++) {
                short8 ap = *(const short8*)&ps[w][c][kstep * 32 + quad * 8];
                #pragma unroll
                for (int dt = 0; dt < 4; dt++) {
                    short8 bv = *(const short8*)&vt[16 * dt + c][64 * kp + kstep * 32 + quad * 8];
                    oacc[dt] = __builtin_amdgcn_mfma_f32_16x16x32_bf16(ap, bv, oacc[dt], 0, 0, 0);
                }
            }
        }
    }

    // ---- epilogue: reduce l over the 16 key-lanes, combine parities, store
    #pragma unroll
    for (int reg = 0; reg < 4; reg++)
        #pragma unroll
        for (int msk = 1; msk < 16; msk <<= 1)
            l[reg] += __shfl_xor(l[reg], msk);

    if (kp == 1) {
        #pragma unroll
        for (int dt = 0; dt < 4; dt++)
            #pragma unroll
            for (int reg = 0; reg < 4; reg++)
                obuf[qh][quad * 4 + reg][16 * dt + c] = oacc[dt][reg];
        if (c == 0)
            #pragma unroll
            for (int reg = 0; reg < 4; reg++)
                lbuf[qh][quad * 4 + reg] = l[reg];
    }
    __syncthreads();
    if (kp == 0) {
        float inv[4];
        #pragma unroll
        for (int reg = 0; reg < 4; reg++)
            inv[reg] = 1.f / (l[reg] + lbuf[qh][quad * 4 + reg]);
        #pragma unroll
        for (int dt = 0; dt < 4; dt++)
            #pragma unroll
            for (int reg = 0; reg < 4; reg++) {
                float o = oacc[dt][reg] + obuf[qh][quad * 4 + reg][16 * dt + c];
                out[(size_t)(b * TT + qrow + quad * 4 + reg) * HS + 16 * dt + c] = o * inv[reg];
            }
    }
}

extern "C" void kernel_launch(void* const* d_in, const int* in_sizes, int n_in,
                              void* d_out, int out_size, void* d_ws, size_t ws_size,
                              hipStream_t stream) {
    const float* x  = (const float*)d_in[0];
    const float* Wq = (const float*)d_in[1];
    const float* Wk = (const float*)d_in[2];
    const float* Wv = (const float*)d_in[3];
    float* out = (float*)d_out;

    unsigned short* Wt = (unsigned short*)d_ws;                  // 3*64*1024 bf16
    unsigned short* qbuf = Wt + 3 * 64 * 1024;
    unsigned short* kbuf = qbuf + (size_t)MM * HS;
    unsigned short* vTb  = kbuf + (size_t)MM * HS;               // [4][64][4096]

    prep_kernel<<<768, 256, 0, stream>>>(Wq, Wk, Wv, Wt);
    qkv_mfma<<<MM / 32, 256, 0, stream>>>(x, Wt, qbuf, kbuf, vTb);
    attn_mfma<<<BB * (TT / 32), 256, 0, stream>>>(qbuf, kbuf, vTb, out);
}

// Round 5
// 136.640 us; speedup vs baseline: 5.5503x; 1.0990x over previous
//
#include <hip/hip_runtime.h>
#include <math.h>

#define BB 4
#define TT 4096
#define CC 1024
#define HS 64
#define MM (BB*TT)   // 16384

typedef __attribute__((ext_vector_type(8))) short short8;    // 8 bf16 (4 VGPR)
typedef __attribute__((ext_vector_type(4))) float f32x4;     // MFMA acc
typedef __attribute__((ext_vector_type(4))) unsigned short ushort4v;

__device__ __forceinline__ unsigned short f2bf(float f) {   // RNE fp32->bf16
    union { float f; unsigned u; } v; v.f = f;
    return (unsigned short)((v.u + 0x7fffu + ((v.u >> 16) & 1u)) >> 16);
}

// ---------------------------------------------------------------------------
// prep: Wt[3][64][1024] = W^T bf16 via coalesced LDS transpose (64x64 tiles).
// Wq pre-scaled by 1/sqrt(HS)=0.125 (exact pow2). Grid 48 = 3 W x 16 k-tiles.
// ---------------------------------------------------------------------------
__global__ __launch_bounds__(256) void prep_kernel(
    const float* __restrict__ Wq, const float* __restrict__ Wk,
    const float* __restrict__ Wv, unsigned short* __restrict__ Wt)
{
    const int which = blockIdx.x >> 4;
    const int k0 = (blockIdx.x & 15) * 64;
    const float* __restrict__ W = (which == 0) ? Wq : (which == 1) ? Wk : Wv;
    const float scale = (which == 0) ? 0.125f : 1.0f;
    __shared__ unsigned short lds[64][65];
    const int t = threadIdx.x;
    #pragma unroll
    for (int i = 0; i < 16; i++) {
        int idx = t + 256 * i;
        int r = idx >> 6, n = idx & 63;           // coalesced read (n fast)
        lds[r][n] = f2bf(W[(size_t)(k0 + r) * 64 + n] * scale);
    }
    __syncthreads();
    #pragma unroll
    for (int i = 0; i < 16; i++) {
        int idx = t + 256 * i;
        int n = idx >> 6, r = idx & 63;           // coalesced write (k fast)
        Wt[(which << 16) + (n << 10) + k0 + r] = lds[r][n];
    }
}

// ---------------------------------------------------------------------------
// qkv_mfma: 32-row m-tile x 192 cols, 512 blocks (2/CU), 256 thr / 4 waves.
// BK=128 (8 chunks: halves barrier-drain count vs BK=64; occupancy is
// grid-limited at 2/CU so the bigger LDS costs nothing). Reg-prefetched.
// V emitted transposed (vT[b][d][t]) via LDS for attn's PV B-fragments.
// LDS row stride 136 bf16 (272B): b128 frag reads land 2-way on banks (free).
// ---------------------------------------------------------------------------
__global__ __launch_bounds__(256, 2) void qkv_mfma(
    const float* __restrict__ x, const unsigned short* __restrict__ Wt,
    unsigned short* __restrict__ qb, unsigned short* __restrict__ kb,
    unsigned short* __restrict__ vT)
{
    const int rt = blockIdx.x;                 // 32-row tile, 512 blocks
    __shared__ unsigned short xs[32][136];     // 32 rows x 128 k
    __shared__ unsigned short ws[192][136];    // 192 n x 128 k (W^T tile)

    const int t = threadIdx.x;
    const int w = t >> 6;
    const int lane = t & 63;
    const int quad = lane >> 4;
    const int c = lane & 15;

    // staging maps: x 4 float4/thread, W 12 short8/thread per 128-chunk
    float4 xreg[4];
    short8 wreg[12];
    #pragma unroll
    for (int i = 0; i < 4; i++) {
        int idx = t + 256 * i;
        int r = idx >> 5, c4 = (idx & 31) * 4;
        xreg[i] = *(const float4*)(x + (size_t)(rt * 32 + r) * CC + c4);
    }
    #pragma unroll
    for (int i = 0; i < 12; i++) {
        int idx = t + 256 * i;
        int n = idx >> 4, c8 = (idx & 15) * 8;
        wreg[i] = *(const short8*)(Wt + (size_t)n * CC + c8);
    }

    f32x4 acc[2][3];
    #pragma unroll
    for (int mt = 0; mt < 2; mt++)
        #pragma unroll
        for (int j = 0; j < 3; j++) acc[mt][j] = (f32x4){0.f, 0.f, 0.f, 0.f};

    for (int k0 = 0; k0 < CC; k0 += 128) {
        __syncthreads();
        #pragma unroll
        for (int i = 0; i < 4; i++) {
            int idx = t + 256 * i;
            int r = idx >> 5, c4 = (idx & 31) * 4;
            ushort4v p = { f2bf(xreg[i].x), f2bf(xreg[i].y), f2bf(xreg[i].z), f2bf(xreg[i].w) };
            *(ushort4v*)&xs[r][c4] = p;
        }
        #pragma unroll
        for (int i = 0; i < 12; i++) {
            int idx = t + 256 * i;
            int n = idx >> 4, c8 = (idx & 15) * 8;
            *(short8*)&ws[n][c8] = wreg[i];
        }
        if (k0 + 128 < CC) {
            #pragma unroll
            for (int i = 0; i < 4; i++) {
                int idx = t + 256 * i;
                int r = idx >> 5, c4 = (idx & 31) * 4;
                xreg[i] = *(const float4*)(x + (size_t)(rt * 32 + r) * CC + k0 + 128 + c4);
            }
            #pragma unroll
            for (int i = 0; i < 12; i++) {
                int idx = t + 256 * i;
                int n = idx >> 4, c8 = (idx & 15) * 8;
                wreg[i] = *(const short8*)(Wt + (size_t)n * CC + k0 + 128 + c8);
            }
        }
        __syncthreads();
        #pragma unroll
        for (int ks = 0; ks < 4; ks++) {
            short8 af[2], bf[3];
            #pragma unroll
            for (int mt = 0; mt < 2; mt++)
                af[mt] = *(const short8*)&xs[16 * mt + c][ks * 32 + quad * 8];
            #pragma unroll
            for (int j = 0; j < 3; j++)
                bf[j] = *(const short8*)&ws[16 * (w + 4 * j) + c][ks * 32 + quad * 8];
            #pragma unroll
            for (int mt = 0; mt < 2; mt++)
                #pragma unroll
                for (int j = 0; j < 3; j++)
                    acc[mt][j] = __builtin_amdgcn_mfma_f32_16x16x32_bf16(af[mt], bf[j], acc[mt][j], 0, 0, 0);
        }
    }

    // epilogue: q,k direct bf16 stores; v -> LDS transpose (reuse ws) -> vT
    __syncthreads();
    unsigned short (*vtb)[72] = (unsigned short (*)[72])ws;   // [d 0..63][t-local 0..31]
    #pragma unroll
    for (int mt = 0; mt < 2; mt++) {
        int grow = rt * 32 + 16 * mt + quad * 4;
        #pragma unroll
        for (int reg = 0; reg < 4; reg++) {
            qb[(size_t)(grow + reg) * HS + 16 * w + c] = f2bf(acc[mt][0][reg]);
            kb[(size_t)(grow + reg) * HS + 16 * w + c] = f2bf(acc[mt][1][reg]);
            vtb[16 * w + c][16 * mt + quad * 4 + reg] = f2bf(acc[mt][2][reg]);
        }
    }
    __syncthreads();
    {
        const int b  = rt >> 7;                 // 128 tiles per batch
        const int t0 = (rt & 127) * 32;
        int d = t >> 2, c8 = (t & 3) * 8;
        short8 v0 = *(const short8*)&vtb[d][c8];
        *(short8*)(vT + (size_t)b * HS * TT + (size_t)d * TT + t0 + c8) = v0;
    }
}

// ---------------------------------------------------------------------------
// attn_mfma: causal flash attention, bf16 MFMA, fixed softmax shift (=0;
// |s|<=~8 so exp fits fp32) -> partials are ADDITIVE. QT=64 (4 waves x 16 q),
// 4-way K-split across blocks: block j handles key-tiles {j, j+4, ...} and
// writes unnormalized (O,l) partials; combine_kernel sums & normalizes.
// Every staged 64-key tile is valid work for all 4 waves (64 MFMA / 16 KB).
// Grid 1024 (qt desc x j x b) = 4 blocks/CU, 16 waves/CU; LDS 28 KB.
// ---------------------------------------------------------------------------
__global__ __launch_bounds__(256, 4) void attn_mfma(
    const unsigned short* __restrict__ qb, const unsigned short* __restrict__ kb,
    const unsigned short* __restrict__ vT, float* __restrict__ Opart,
    float* __restrict__ lpart)
{
    const int bid = blockIdx.x;
    const int qt = (TT / 64 - 1) - (bid >> 4);   // 64-row q-tile, descending
    const int j  = (bid >> 2) & 3;               // K-split index
    const int b  = bid & 3;

    __shared__ unsigned short ks[64][72];      // [key][d]
    __shared__ unsigned short vt[64][72];      // [d][key]
    __shared__ unsigned short ps[4][16][72];   // per-wave P [q][key]

    const int t = threadIdx.x;
    const int w = t >> 6;
    const int lane = t & 63;
    const int quad = lane >> 4;
    const int c = lane & 15;
    const int qrow = qt * 64 + 16 * w;         // wave's first query row

    // Q A-frags resident in registers
    short8 aq[2];
    #pragma unroll
    for (int kstep = 0; kstep < 2; kstep++)
        aq[kstep] = *(const short8*)(qb + (size_t)(b * TT + qrow + c) * HS + kstep * 32 + quad * 8);

    const int nkt = (qt >= j) ? ((qt - j) >> 2) + 1 : 0;
    const unsigned short* Kb = kb + (size_t)b * TT * HS;
    const unsigned short* Vb = vT + (size_t)b * HS * TT;

    // staging maps: 2 short8/thread each for K and V (64x64 bf16 tiles)
    const int srow = t >> 3;                   // 0..31 (+32 for i=1)
    const int sc8  = (t & 7) * 8;

    short8 kreg[2], vreg[2];
    if (nkt > 0) {
        const int kt0 = j * 64;
        #pragma unroll
        for (int i = 0; i < 2; i++) {
            kreg[i] = *(const short8*)(Kb + (size_t)(kt0 + srow + 32 * i) * HS + sc8);
            vreg[i] = *(const short8*)(Vb + (size_t)(srow + 32 * i) * TT + kt0 + sc8);
        }
    }

    float l[4] = {0.f, 0.f, 0.f, 0.f};
    f32x4 oacc[4];
    #pragma unroll
    for (int dt = 0; dt < 4; dt++) oacc[dt] = (f32x4){0.f, 0.f, 0.f, 0.f};

    for (int i = 0; i < nkt; i++) {
        const int kt = j + 4 * i;
        const int kt0 = kt * 64;
        __syncthreads();   // prev compute done reading ks/vt
        #pragma unroll
        for (int ii = 0; ii < 2; ii++) {
            *(short8*)&ks[srow + 32 * ii][sc8] = kreg[ii];
            *(short8*)&vt[srow + 32 * ii][sc8] = vreg[ii];
        }
        if (i + 1 < nkt) {
            const int nb = kt0 + 256;
            #pragma unroll
            for (int ii = 0; ii < 2; ii++) {
                kreg[ii] = *(const short8*)(Kb + (size_t)(nb + srow + 32 * ii) * HS + sc8);
                vreg[ii] = *(const short8*)(Vb + (size_t)(srow + 32 * ii) * TT + nb + sc8);
            }
        }
        __syncthreads();   // ks/vt visible

        // ---- scores
        f32x4 sc[4];
        #pragma unroll
        for (int st = 0; st < 4; st++) sc[st] = (f32x4){0.f, 0.f, 0.f, 0.f};
        #pragma unroll
        for (int kstep = 0; kstep < 2; kstep++) {
            #pragma unroll
            for (int st = 0; st < 4; st++) {
                short8 bf = *(const short8*)&ks[16 * st + c][kstep * 32 + quad * 8];
                sc[st] = __builtin_amdgcn_mfma_f32_16x16x32_bf16(aq[kstep], bf, sc[st], 0, 0, 0);
            }
        }
        // ---- p = exp(s); mask only the diagonal tile (kt == qt)
        if (kt == qt) {
            #pragma unroll
            for (int st = 0; st < 4; st++)
                #pragma unroll
                for (int reg = 0; reg < 4; reg++) {
                    int kg = kt0 + 16 * st + c;
                    int qg = qrow + quad * 4 + reg;
                    float p = (kg <= qg) ? __expf(sc[st][reg]) : 0.f;
                    sc[st][reg] = p;
                    l[reg] += p;
                }
        } else {
            #pragma unroll
            for (int st = 0; st < 4; st++)
                #pragma unroll
                for (int reg = 0; reg < 4; reg++) {
                    float p = __expf(sc[st][reg]);
                    sc[st][reg] = p;
                    l[reg] += p;
                }
        }
        // ---- P -> per-wave LDS (C-layout write, A-layout read; same wave)
        #pragma unroll
        for (int st = 0; st < 4; st++)
            #pragma unroll
            for (int reg = 0; reg < 4; reg++)
                ps[w][quad * 4 + reg][16 * st + c] = f2bf(sc[st][reg]);

        // ---- PV accumulate (unnormalized)
        #pragma unroll
        for (int kstep = 0; kstep < 2; kstep++) {
            short8 ap = *(const short8*)&ps[w][c][kstep * 32 + quad * 8];
            #pragma unroll
            for (int dt = 0; dt < 4; dt++) {
                short8 bv = *(const short8*)&vt[16 * dt + c][kstep * 32 + quad * 8];
                oacc[dt] = __builtin_amdgcn_mfma_f32_16x16x32_bf16(ap, bv, oacc[dt], 0, 0, 0);
            }
        }
    }

    // ---- epilogue: reduce l over 16 key-lanes, write unnormalized partials
    #pragma unroll
    for (int reg = 0; reg < 4; reg++)
        #pragma unroll
        for (int msk = 1; msk < 16; msk <<= 1)
            l[reg] += __shfl_xor(l[reg], msk);

    float* __restrict__ Oj = Opart + (size_t)j * MM * HS;
    #pragma unroll
    for (int dt = 0; dt < 4; dt++)
        #pragma unroll
        for (int reg = 0; reg < 4; reg++)
            Oj[(size_t)(b * TT + qrow + quad * 4 + reg) * HS + 16 * dt + c] = oacc[dt][reg];
    if (c == 0)
        #pragma unroll
        for (int reg = 0; reg < 4; reg++)
            lpart[(size_t)j * MM + b * TT + qrow + quad * 4 + reg] = l[reg];
}

// ---------------------------------------------------------------------------
// combine: out = (sum_j O_j) / (sum_j l_j). 262144 float4s, grid 1024.
// ---------------------------------------------------------------------------
__global__ __launch_bounds__(256) void combine_kernel(
    const float* __restrict__ Opart, const float* __restrict__ lpart,
    float* __restrict__ out)
{
    const int id = blockIdx.x * 256 + threadIdx.x;   // 0 .. MM*HS/4-1
    const int row = id >> 4;
    float l = lpart[row] + lpart[MM + row] + lpart[2 * MM + row] + lpart[3 * MM + row];
    const float4* O = (const float4*)Opart;
    const size_t stride = (size_t)MM * HS / 4;
    float4 a = O[id], b = O[id + stride], c = O[id + 2 * stride], d = O[id + 3 * stride];
    float inv = 1.f / l;
    float4 r;
    r.x = (a.x + b.x + c.x + d.x) * inv;
    r.y = (a.y + b.y + c.y + d.y) * inv;
    r.z = (a.z + b.z + c.z + d.z) * inv;
    r.w = (a.w + b.w + c.w + d.w) * inv;
    ((float4*)out)[id] = r;
}

extern "C" void kernel_launch(void* const* d_in, const int* in_sizes, int n_in,
                              void* d_out, int out_size, void* d_ws, size_t ws_size,
                              hipStream_t stream) {
    const float* x  = (const float*)d_in[0];
    const float* Wq = (const float*)d_in[1];
    const float* Wk = (const float*)d_in[2];
    const float* Wv = (const float*)d_in[3];
    float* out = (float*)d_out;

    unsigned short* Wt   = (unsigned short*)d_ws;            // 384 KB
    unsigned short* qbuf = Wt + 3 * 64 * 1024;               // 2 MB each
    unsigned short* kbuf = qbuf + (size_t)MM * HS;
    unsigned short* vTb  = kbuf + (size_t)MM * HS;           // [4][64][4096]
    float* Opart = (float*)(vTb + (size_t)MM * HS);          // 4 x 4 MB
    float* lpart = Opart + 4 * (size_t)MM * HS;              // 256 KB

    prep_kernel<<<48, 256, 0, stream>>>(Wq, Wk, Wv, Wt);
    qkv_mfma<<<MM / 32, 256, 0, stream>>>(x, Wt, qbuf, kbuf, vTb);
    attn_mfma<<<BB * (TT / 64) * 4, 256, 0, stream>>>(qbuf, kbuf, vTb, Opart, lpart);
    combine_kernel<<<1024, 256, 0, stream>>>(Opart, lpart, out);
}